// Round 8
// baseline (209.877 us; speedup 1.0000x reference)
//
#include <hip/hip_runtime.h>
#include <cstdint>

#define B 16
#define H 128
#define W 128
#define NC 80
#define PB (H*W*NC)
#define K 100
#define NSUB 16          // sub-counters per batch (atomic distribution)
#define SEGCAP 1024      // candidate slots per (batch, sub)
#define THRESH 0.95f
#define NBINS 4096
#define LISTCAP 512
#define TY 16            // output rows per wave-tile
#define OX 14            // output cols per wave-tile (16 loaded, 14 emitted)
#define YT (H/TY)        // 8
#define XT 10            // ceil(W/OX)
#define BPB (YT*XT)      // 80 blocks per batch
#define NBLK (B*BPB)     // 1280

__device__ unsigned long long g_cand[B * NSUB * SEGCAP];   // 2 MB
__device__ int g_counts[B * NSUB * 16] = {};  // 64B-strided; finisher re-zeros
__device__ int g_done[B * 16] = {};           // 64B-strided; finisher re-zeros

__device__ __forceinline__ float sigmoidf(float x) {
    return 1.0f / (1.0f + expf(-x));
}
__device__ __forceinline__ float4 f4max2(float4 a, float4 b) {
    float4 r;
    r.x = fmaxf(a.x, b.x); r.y = fmaxf(a.y, b.y);
    r.z = fmaxf(a.z, b.z); r.w = fmaxf(a.w, b.w);
    return r;
}
__device__ __forceinline__ float4 shfl4(float4 v, int src) {
    float4 r;
    r.x = __shfl(v.x, src);
    r.y = __shfl(v.y, src);
    r.z = __shfl(v.z, src);
    r.w = __shfl(v.w, src);
    return r;
}

// Fused: sigmoid + 3x3 peak NMS + compaction, then per-batch top-K run by the
// LAST finishing block of each batch (done-counter + device fences).
// Peak phase: one wave per (b, 16-row, 14-col overlapped, 16-class group);
// ALL 18 rows preloaded into NAMED registers under __launch_bounds__(320,1)
// (r4 lesson: launch_bounds w/o min-waves arg capped VGPR=32 -> scratch spill;
// (320,1) lifts the cap so 18 float4 stay in registers, MLP=18/wave).
__global__ __launch_bounds__(320, 1)
void fused_kernel(const float* __restrict__ cls,
                  const float* __restrict__ dxy,
                  const float* __restrict__ swh,
                  float* __restrict__ out) {
    const int raw = blockIdx.x;                          // 1280
    const int blk = (raw & 7) * (NBLK / 8) + (raw >> 3); // XCD-contiguous ranges
    const int b   = blk / BPB;
    const int rem = blk - b * BPB;
    const int yt  = rem / XT;
    const int xt  = rem - yt * XT;
    const int sub = rem & (NSUB - 1);                    // 16-way atomic distribution
    const int tid  = threadIdx.x;
    const int lane = tid & 63;
    const int cg   = tid >> 6;                           // class group 0..4
    const int c4   = lane & 3;
    const int xl   = lane >> 2;                          // 0..15
    const int xg   = xt * OX - 1 + xl;                   // global col, may be OOB
    const int y0   = yt * TY;
    const int cbase = cg * 16 + c4 * 4;

    int* const cnt_p = &g_counts[(b * NSUB + sub) * 16];
    unsigned long long* const seg_p = &g_cand[(size_t)(b * NSUB + sub) * SEGCAP];

    const float NI = -__builtin_inff();
    const float4 NEG = make_float4(NI, NI, NI, NI);
    const float* bp = cls + (size_t)b * PB + cbase;

    const bool xv = (xg >= 0) & (xg < W);
    const bool emitOK = (xl >= 1) & (xl <= OX) & (xg < W);

    const int lsrcL = (lane - 4) & 63;
    const int lsrcR = (lane + 4) & 63;

    auto ld = [&](int j) -> float4 {                     // raw row j (y = y0-1+j)
        const int y = y0 - 1 + j;
        const bool ok = (y >= 0) & (y < H) & xv;
        return ok ? *(const float4*)(bp + (size_t)(y * W + xg) * NC) : NEG;
    };

    // 18 named preloads: 18 loads in flight, monotone vmcnt drain.
    float4 w0 = ld(0),  w1 = ld(1),  w2 = ld(2),  w3 = ld(3),  w4 = ld(4);
    float4 w5 = ld(5),  w6 = ld(6),  w7 = ld(7),  w8 = ld(8),  w9 = ld(9);
    float4 w10 = ld(10), w11 = ld(11), w12 = ld(12), w13 = ld(13), w14 = ld(14);
    float4 w15 = ld(15), w16 = ld(16), w17 = ld(17);

    float4 pair = f4max2(w0, w1);                        // max(rows k, k+1)

    auto step = [&](const float4& ctr, const float4& bot, int k) {
        float4 v3 = f4max2(pair, bot);                   // vertical 3-max, own col
        float cmax = fmaxf(fmaxf(ctr.x, ctr.y), fmaxf(ctr.z, ctr.w));
        const bool pre = emitOK & (cmax > 2.9f);         // candidate needs own v>2.9
        if (__any(pre)) {                                // wave-uniform skip
            float4 Lv = shfl4(v3, lsrcL);
            float4 Rv = shfl4(v3, lsrcR);
            float4 vm4 = f4max2(f4max2(Lv, Rv), v3);     // full 3x3 max (exact)
            if (pre) {
                const int yo = y0 + k;
                float vv[4] = { ctr.x, ctr.y, ctr.z, ctr.w };
                float mm[4] = { vm4.x, vm4.y, vm4.z, vm4.w };
                #pragma unroll
                for (int c = 0; c < 4; ++c) {
                    float v = vv[c], vm = mm[c];
                    // logit prefilter band 1e-3 >> worst-case sigmoid
                    // rounding-collision window (~1.5e-5)
                    if (v > 2.9f && (vm - v) <= 1e-3f) {
                        float sc = sigmoidf(v);
                        float sm = sigmoidf(vm);         // monotone: = max sigmoid
                        if (sc == sm && sc > THRESH) {
                            unsigned ib = ((unsigned)(yo * W + xg)) * NC + cbase + c;
                            unsigned long long key =
                                ((unsigned long long)__float_as_uint(sc) << 32) |
                                (unsigned long long)(0xFFFFFFFFu - ib);
                            int slot = atomicAdd(cnt_p, 1);
                            if (slot < SEGCAP) seg_p[slot] = key;
                        }
                    }
                }
            }
        }
        pair = f4max2(ctr, bot);                         // pair for next step
    };

    step(w1, w2, 0);   step(w2, w3, 1);   step(w3, w4, 2);   step(w4, w5, 3);
    step(w5, w6, 4);   step(w6, w7, 5);   step(w7, w8, 6);   step(w8, w9, 7);
    step(w9, w10, 8);  step(w10, w11, 9); step(w11, w12, 10); step(w12, w13, 11);
    step(w13, w14, 12); step(w14, w15, 13); step(w15, w16, 14); step(w16, w17, 15);

    // ---- finisher handoff: last block of batch b runs the top-K ----
    __shared__ int hist[NBINS];
    __shared__ int csum[256];
    __shared__ int segn[NSUB];
    __shared__ unsigned long long list[LISTCAP];
    __shared__ int lcount;
    __shared__ int kstar;
    __shared__ int lastflag;

    __syncthreads();                       // all waves' emits issued
    if (tid == 0) {
        __threadfence();                   // release g_cand/g_counts writes
        int prev = atomicAdd(&g_done[b * 16], 1);
        lastflag = (prev == BPB - 1);
    }
    __syncthreads();
    if (!lastflag) return;
    __threadfence();                       // acquire other blocks' writes

    if (tid < NSUB) {
        int n = g_counts[(b * NSUB + tid) * 16];
        segn[tid] = n > SEGCAP ? SEGCAP : n;
    }
    for (int i = tid; i < NBINS; i += 320) hist[i] = 0;
    if (tid == 0) lcount = 0;
    __syncthreads();

    const float SCALE = (float)NBINS / (1.0f - THRESH);
    #pragma unroll 1
    for (int s = 0; s < NSUB; ++s) {
        const unsigned long long* cb = g_cand + (size_t)(b * NSUB + s) * SEGCAP;
        const int n = segn[s];
        for (int i = tid; i < n; i += 320) {
            float v = __uint_as_float((unsigned)(cb[i] >> 32));
            int bin = (int)((v - THRESH) * SCALE);
            bin = bin < 0 ? 0 : (bin > NBINS - 1 ? NBINS - 1 : bin);
            atomicAdd(&hist[bin], 1);
        }
    }
    __syncthreads();

    if (tid < 256) {
        int s0 = 0;
        for (int j = 0; j < NBINS / 256; j++) s0 += hist[tid * (NBINS / 256) + j];
        csum[tid] = s0;
    }
    __syncthreads();

    if (tid == 0) {
        int acc = 0;
        int chunk = 255;
        for (; chunk >= 0; chunk--) {
            if (acc + csum[chunk] >= K) break;
            acc += csum[chunk];
        }
        int ks = 0;
        if (chunk >= 0) {
            int j = NBINS / 256 - 1;
            for (; j >= 0; j--) {
                acc += hist[chunk * (NBINS / 256) + j];
                if (acc >= K) break;
            }
            if (j < 0) j = 0;
            ks = chunk * (NBINS / 256) + j;
        }
        kstar = ks;
    }
    __syncthreads();

    const int ks = kstar;
    #pragma unroll 1
    for (int s = 0; s < NSUB; ++s) {
        const unsigned long long* cb = g_cand + (size_t)(b * NSUB + s) * SEGCAP;
        const int n = segn[s];
        for (int i = tid; i < n; i += 320) {
            unsigned long long key = cb[i];
            float v = __uint_as_float((unsigned)(key >> 32));
            int bin = (int)((v - THRESH) * SCALE);
            bin = bin < 0 ? 0 : (bin > NBINS - 1 ? NBINS - 1 : bin);
            if (bin >= ks) {
                int p = atomicAdd(&lcount, 1);
                if (p < LISTCAP) list[p] = key;
            }
        }
    }
    __syncthreads();
    const int M = lcount < LISTCAP ? lcount : LISTCAP;

    // exact rank by counting (keys distinct: low 32 bits unique per batch)
    for (int i = tid; i < M; i += 320) {
        unsigned long long key = list[i];
        int rank = 0;
        for (int j = 0; j < M; j++) rank += (list[j] > key);
        if (rank < K) {
            float conf = __uint_as_float((unsigned)(key >> 32));
            unsigned ib = 0xFFFFFFFFu - (unsigned)(key & 0xFFFFFFFFu);
            unsigned cls_i = ib % (unsigned)NC;
            unsigned sidx = ib / (unsigned)NC;
            unsigned xq = sidx & (W - 1);
            unsigned yq = sidx >> 7;

            size_t goff = ((size_t)b * (H * W) + sidx) * 2;
            float dx = dxy[goff], dy = dxy[goff + 1];
            float sw = swh[goff], sh = swh[goff + 1];

            float xs = (float)xq + dx;
            float ys = (float)yq + dy;
            float hw = sw * 0.5f;
            float hh = sh * 0.5f;
            const float invW = 1.0f / (float)W;
            const float invH = 1.0f / (float)H;

            int r = b * K + rank;
            out[r * 4 + 0] = (xs - hw) * invW;
            out[r * 4 + 1] = (ys - hh) * invH;
            out[r * 4 + 2] = (xs + hw) * invW;
            out[r * 4 + 3] = (ys + hh) * invH;
            out[B * K * 4 + r] = conf;
            out[B * K * 4 + B * K + r] = (float)cls_i;
        }
    }

    __syncthreads();
    if (tid < NSUB) g_counts[(b * NSUB + tid) * 16] = 0;   // reset for next call
    if (tid == 0) g_done[b * 16] = 0;
}

extern "C" void kernel_launch(void* const* d_in, const int* in_sizes, int n_in,
                              void* d_out, int out_size, void* d_ws, size_t ws_size,
                              hipStream_t stream) {
    const float* cls = (const float*)d_in[0];
    const float* dxy = (const float*)d_in[1];
    const float* swh = (const float*)d_in[2];
    float* out = (float*)d_out;

    fused_kernel<<<NBLK, 320, 0, stream>>>(cls, dxy, swh, out);
}

// Round 9
// 157.321 us; speedup vs baseline: 1.3341x; 1.3341x over previous
//
#include <hip/hip_runtime.h>
#include <cstdint>

#define B 16
#define H 128
#define W 128
#define NC 80
#define PB (H*W*NC)
#define K 100
#define NSUB 16          // sub-counters per batch (atomic distribution)
#define SEGCAP 1024      // candidate slots per (batch, sub)
#define THRESH 0.95f
#define NBINS 4096
#define LISTCAP 512
#define TY 16            // output rows per wave-tile
#define OX 14            // output cols per wave-tile (16 loaded, 14 emitted)
#define YT (H/TY)        // 8
#define XT 10            // ceil(W/OX)
#define NBLK (B*YT*XT)   // 1280

__device__ unsigned long long g_cand[B * NSUB * SEGCAP];   // 2 MB
__device__ int g_counts[B * NSUB * 16] = {};  // 64B-strided; zeroed at load; topk re-zeros

__device__ __forceinline__ float sigmoidf(float x) {
    return 1.0f / (1.0f + expf(-x));
}
__device__ __forceinline__ float4 f4max2(float4 a, float4 b) {
    float4 r;
    r.x = fmaxf(a.x, b.x); r.y = fmaxf(a.y, b.y);
    r.z = fmaxf(a.z, b.z); r.w = fmaxf(a.w, b.w);
    return r;
}
__device__ __forceinline__ float4 shfl4(float4 v, int src) {
    float4 r;
    r.x = __shfl(v.x, src);
    r.y = __shfl(v.y, src);
    r.z = __shfl(v.z, src);
    r.w = __shfl(v.w, src);
    return r;
}

// Stage A: fused sigmoid + 3x3 peak NMS + compaction.
// One wave per (b, 16-row y-tile, 14-col overlapped x-tile, 16-class group).
// No LDS/barriers; no edge loads (16 cols loaded, middle 14 emitted).
// Round-9: __launch_bounds__(320,2) lifts the VGPR cap to 256 — every prior
// build compiled at VGPR 28-48, silently squeezing the load pipeline to ~2-3
// in flight. 8-slot named rotation, prefetch distance 7 (7 loads in flight,
// monotone vmcnt drain). Ballot-skip + XCD swizzle + 16-way atomics kept.
__global__ __launch_bounds__(320, 2) void peak_kernel(const float* __restrict__ cls) {
    const int raw = blockIdx.x;                          // 1280
    const int blk = (raw & 7) * (NBLK / 8) + (raw >> 3); // XCD-contiguous ranges
    const int b   = blk / (YT * XT);
    const int rem = blk - b * (YT * XT);
    const int yt  = rem / XT;
    const int xt  = rem - yt * XT;
    const int sub = rem & (NSUB - 1);                    // 16-way atomic distribution
    const int lane = threadIdx.x & 63;
    const int cg   = threadIdx.x >> 6;                   // class group 0..4
    const int c4   = lane & 3;
    const int xl   = lane >> 2;                          // 0..15
    const int xg   = xt * OX - 1 + xl;                   // global col, may be OOB
    const int y0   = yt * TY;
    const int cbase = cg * 16 + c4 * 4;

    int* const cnt_p = &g_counts[(b * NSUB + sub) * 16];
    unsigned long long* const seg_p = &g_cand[(size_t)(b * NSUB + sub) * SEGCAP];

    const float NI = -__builtin_inff();
    const float4 NEG = make_float4(NI, NI, NI, NI);
    const float* bp = cls + (size_t)b * PB + cbase;

    const bool xv = (xg >= 0) & (xg < W);
    const bool emitOK = (xl >= 1) & (xl <= OX) & (xg < W);

    const int lsrcL = (lane - 4) & 63;
    const int lsrcR = (lane + 4) & 63;

    auto ld = [&](int j) -> float4 {                     // raw row j (y = y0-1+j)
        const int y = y0 - 1 + j;
        const bool ok = (y >= 0) & (y < H) & xv;
        return ok ? *(const float4*)(bp + (size_t)(y * W + xg) * NC) : NEG;
    };

    // 8 named slots; rows 0..6 preloaded -> 7 loads in flight steady-state.
    float4 w0 = ld(0), w1 = ld(1), w2 = ld(2), w3 = ld(3);
    float4 w4 = ld(4), w5 = ld(5), w6 = ld(6), w7;

    float4 pair = f4max2(w0, w1);                        // max(rows k, k+1)

    auto step = [&](const float4& ctr, const float4& bot, float4& fre, int k) {
        if (k + 7 <= TY + 1) fre = ld(k + 7);            // prefetch row k+7
        float4 v3 = f4max2(pair, bot);                   // vertical 3-max, own col
        float cmax = fmaxf(fmaxf(ctr.x, ctr.y), fmaxf(ctr.z, ctr.w));
        const bool pre = emitOK & (cmax > 2.9f);         // candidate needs own v>2.9
        if (__any(pre)) {                                // wave-uniform skip
            float4 Lv = shfl4(v3, lsrcL);
            float4 Rv = shfl4(v3, lsrcR);
            float4 vm4 = f4max2(f4max2(Lv, Rv), v3);     // full 3x3 max (exact)
            if (pre) {
                const int yo = y0 + k;
                float vv[4] = { ctr.x, ctr.y, ctr.z, ctr.w };
                float mm[4] = { vm4.x, vm4.y, vm4.z, vm4.w };
                #pragma unroll
                for (int c = 0; c < 4; ++c) {
                    float v = vv[c], vm = mm[c];
                    // logit prefilter band 1e-3 >> worst-case sigmoid
                    // rounding-collision window (~1.5e-5)
                    if (v > 2.9f && (vm - v) <= 1e-3f) {
                        float sc = sigmoidf(v);
                        float sm = sigmoidf(vm);         // monotone: = max sigmoid
                        if (sc == sm && sc > THRESH) {
                            unsigned ib = ((unsigned)(yo * W + xg)) * NC + cbase + c;
                            unsigned long long key =
                                ((unsigned long long)__float_as_uint(sc) << 32) |
                                (unsigned long long)(0xFFFFFFFFu - ib);
                            int slot = atomicAdd(cnt_p, 1);
                            if (slot < SEGCAP) seg_p[slot] = key;
                        }
                    }
                }
            }
        }
        pair = f4max2(ctr, bot);                         // pair for next step
    };

    // step k: ctr=row k+1 (slot (k+1)&7), bot=row k+2, fill slot (k+7)&7.
    step(w1, w2, w7, 0);   step(w2, w3, w0, 1);   step(w3, w4, w1, 2);
    step(w4, w5, w2, 3);   step(w5, w6, w3, 4);   step(w6, w7, w4, 5);
    step(w7, w0, w5, 6);   step(w0, w1, w6, 7);   step(w1, w2, w7, 8);
    step(w2, w3, w0, 9);   step(w3, w4, w1, 10);  step(w4, w5, w2, 11);
    step(w5, w6, w3, 12);  step(w6, w7, w4, 13);  step(w7, w0, w5, 14);
    step(w0, w1, w6, 15);
}

// Stage B: per-batch exact top-K over 16 segments
// (histogram cutoff -> collect -> rank-by-count -> decode)
__global__ __launch_bounds__(256) void topk_kernel(const float* __restrict__ dxy,
                                                   const float* __restrict__ swh,
                                                   float* __restrict__ out) {
    const int b = blockIdx.x;
    const int tid = threadIdx.x;
    __shared__ int hist[NBINS];
    __shared__ int csum[256];
    __shared__ int segn[NSUB];
    __shared__ unsigned long long list[LISTCAP];
    __shared__ int lcount;
    __shared__ int kstar;

    if (tid < NSUB) {
        int n = g_counts[(b * NSUB + tid) * 16];
        segn[tid] = n > SEGCAP ? SEGCAP : n;
    }
    for (int i = tid; i < NBINS; i += 256) hist[i] = 0;
    if (tid == 0) lcount = 0;
    __syncthreads();

    const float SCALE = (float)NBINS / (1.0f - THRESH);
    #pragma unroll 1
    for (int s = 0; s < NSUB; ++s) {
        const unsigned long long* cb = g_cand + (size_t)(b * NSUB + s) * SEGCAP;
        const int n = segn[s];
        for (int i = tid; i < n; i += 256) {
            float v = __uint_as_float((unsigned)(cb[i] >> 32));
            int bin = (int)((v - THRESH) * SCALE);
            bin = bin < 0 ? 0 : (bin > NBINS - 1 ? NBINS - 1 : bin);
            atomicAdd(&hist[bin], 1);
        }
    }
    __syncthreads();

    int s0 = 0;
    for (int j = 0; j < NBINS / 256; j++) s0 += hist[tid * (NBINS / 256) + j];
    csum[tid] = s0;
    __syncthreads();

    if (tid == 0) {
        int acc = 0;
        int chunk = 255;
        for (; chunk >= 0; chunk--) {
            if (acc + csum[chunk] >= K) break;
            acc += csum[chunk];
        }
        int ks = 0;
        if (chunk >= 0) {
            int j = NBINS / 256 - 1;
            for (; j >= 0; j--) {
                acc += hist[chunk * (NBINS / 256) + j];
                if (acc >= K) break;
            }
            if (j < 0) j = 0;
            ks = chunk * (NBINS / 256) + j;
        }
        kstar = ks;
    }
    __syncthreads();

    const int ks = kstar;
    #pragma unroll 1
    for (int s = 0; s < NSUB; ++s) {
        const unsigned long long* cb = g_cand + (size_t)(b * NSUB + s) * SEGCAP;
        const int n = segn[s];
        for (int i = tid; i < n; i += 256) {
            unsigned long long key = cb[i];
            float v = __uint_as_float((unsigned)(key >> 32));
            int bin = (int)((v - THRESH) * SCALE);
            bin = bin < 0 ? 0 : (bin > NBINS - 1 ? NBINS - 1 : bin);
            if (bin >= ks) {
                int p = atomicAdd(&lcount, 1);
                if (p < LISTCAP) list[p] = key;
            }
        }
    }
    __syncthreads();
    const int M = lcount < LISTCAP ? lcount : LISTCAP;

    // exact rank by counting (keys distinct: low 32 bits unique per batch)
    for (int i = tid; i < M; i += 256) {
        unsigned long long key = list[i];
        int rank = 0;
        for (int j = 0; j < M; j++) rank += (list[j] > key);
        if (rank < K) {
            float conf = __uint_as_float((unsigned)(key >> 32));
            unsigned ib = 0xFFFFFFFFu - (unsigned)(key & 0xFFFFFFFFu);
            unsigned cls_i = ib % (unsigned)NC;
            unsigned sidx = ib / (unsigned)NC;
            unsigned xq = sidx & (W - 1);
            unsigned yq = sidx >> 7;

            size_t goff = ((size_t)b * (H * W) + sidx) * 2;
            float dx = dxy[goff], dy = dxy[goff + 1];
            float sw = swh[goff], sh = swh[goff + 1];

            float xs = (float)xq + dx;
            float ys = (float)yq + dy;
            float hw = sw * 0.5f;
            float hh = sh * 0.5f;
            const float invW = 1.0f / (float)W;
            const float invH = 1.0f / (float)H;

            int r = b * K + rank;
            out[r * 4 + 0] = (xs - hw) * invW;
            out[r * 4 + 1] = (ys - hh) * invH;
            out[r * 4 + 2] = (xs + hw) * invW;
            out[r * 4 + 3] = (ys + hh) * invH;
            out[B * K * 4 + r] = conf;
            out[B * K * 4 + B * K + r] = (float)cls_i;
        }
    }

    __syncthreads();
    if (tid < NSUB) g_counts[(b * NSUB + tid) * 16] = 0;   // reset for next call
}

extern "C" void kernel_launch(void* const* d_in, const int* in_sizes, int n_in,
                              void* d_out, int out_size, void* d_ws, size_t ws_size,
                              hipStream_t stream) {
    const float* cls = (const float*)d_in[0];
    const float* dxy = (const float*)d_in[1];
    const float* swh = (const float*)d_in[2];
    float* out = (float*)d_out;

    peak_kernel<<<NBLK, 320, 0, stream>>>(cls);
    topk_kernel<<<B, 256, 0, stream>>>(dxy, swh, out);
}

// Round 10
// 152.972 us; speedup vs baseline: 1.3720x; 1.0284x over previous
//
#include <hip/hip_runtime.h>
#include <cstdint>

#define B 16
#define H 128
#define W 128
#define NC 80
#define PB (H*W*NC)
#define K 100
#define NSUB 16          // sub-counters per batch (atomic distribution)
#define SEGCAP 1024      // candidate slots per (batch, sub)
#define THRESH 0.95f
#define NBINS 4096
#define LISTCAP 512
#define LBUF 256         // per-block LDS candidate buffer (exp ~26/block)
#define TY 16            // output rows per wave-tile
#define OX 14            // output cols per wave-tile (16 loaded, 14 emitted)
#define YT (H/TY)        // 8
#define XT 10            // ceil(W/OX)
#define NBLK (B*YT*XT)   // 1280

__device__ unsigned long long g_cand[B * NSUB * SEGCAP];   // 2 MB
__device__ int g_counts[B * NSUB * 16] = {};  // 64B-strided; zeroed at load; topk re-zeros

__device__ __forceinline__ float sigmoidf(float x) {
    return 1.0f / (1.0f + expf(-x));
}
__device__ __forceinline__ float4 f4max2(float4 a, float4 b) {
    float4 r;
    r.x = fmaxf(a.x, b.x); r.y = fmaxf(a.y, b.y);
    r.z = fmaxf(a.z, b.z); r.w = fmaxf(a.w, b.w);
    return r;
}
__device__ __forceinline__ float4 shfl4(float4 v, int src) {
    float4 r;
    r.x = __shfl(v.x, src);
    r.y = __shfl(v.y, src);
    r.z = __shfl(v.z, src);
    r.w = __shfl(v.w, src);
    return r;
}

// Stage A: fused sigmoid + 3x3 peak NMS + compaction.
// One wave per (b, 16-row y-tile, 14-col overlapped x-tile, 16-class group).
// Round-10: mid-loop emission goes to LDS (ds_atomic + ds_write = lgkmcnt
// domain — does NOT drain the vmcnt prefetch queue like the old global
// atomicAdd->waitcnt->store chain did, ~5x per wave). One global atomic +
// coalesced flush per block at the end (33k global atomics -> 1280).
__global__ __launch_bounds__(320, 2) void peak_kernel(const float* __restrict__ cls) {
    const int raw = blockIdx.x;                          // 1280
    const int blk = (raw & 7) * (NBLK / 8) + (raw >> 3); // XCD-contiguous ranges
    const int b   = blk / (YT * XT);
    const int rem = blk - b * (YT * XT);
    const int yt  = rem / XT;
    const int xt  = rem - yt * XT;
    const int sub = rem & (NSUB - 1);                    // 16-way atomic distribution
    const int tid  = threadIdx.x;
    const int lane = tid & 63;
    const int cg   = tid >> 6;                           // class group 0..4
    const int c4   = lane & 3;
    const int xl   = lane >> 2;                          // 0..15
    const int xg   = xt * OX - 1 + xl;                   // global col, may be OOB
    const int y0   = yt * TY;
    const int cbase = cg * 16 + c4 * 4;

    __shared__ unsigned long long lbuf[LBUF];
    __shared__ int lcnt;
    __shared__ int sbase;
    if (tid == 0) lcnt = 0;
    __syncthreads();

    int* const cnt_p = &g_counts[(b * NSUB + sub) * 16];
    unsigned long long* const seg_p = &g_cand[(size_t)(b * NSUB + sub) * SEGCAP];

    const float NI = -__builtin_inff();
    const float4 NEG = make_float4(NI, NI, NI, NI);
    const float* bp = cls + (size_t)b * PB + cbase;

    const bool xv = (xg >= 0) & (xg < W);
    const bool emitOK = (xl >= 1) & (xl <= OX) & (xg < W);

    const int lsrcL = (lane - 4) & 63;
    const int lsrcR = (lane + 4) & 63;

    auto ld = [&](int j) -> float4 {                     // raw row j (y = y0-1+j)
        const int y = y0 - 1 + j;
        const bool ok = (y >= 0) & (y < H) & xv;
        return ok ? *(const float4*)(bp + (size_t)(y * W + xg) * NC) : NEG;
    };

    // 8 named slots; rows 0..6 preloaded -> 7 loads in flight steady-state.
    float4 w0 = ld(0), w1 = ld(1), w2 = ld(2), w3 = ld(3);
    float4 w4 = ld(4), w5 = ld(5), w6 = ld(6), w7;

    float4 pair = f4max2(w0, w1);                        // max(rows k, k+1)

    auto step = [&](const float4& ctr, const float4& bot, float4& fre, int k) {
        if (k + 7 <= TY + 1) fre = ld(k + 7);            // prefetch row k+7
        float4 v3 = f4max2(pair, bot);                   // vertical 3-max, own col
        float cmax = fmaxf(fmaxf(ctr.x, ctr.y), fmaxf(ctr.z, ctr.w));
        const bool pre = emitOK & (cmax > 2.9f);         // candidate needs own v>2.9
        if (__any(pre)) {                                // wave-uniform skip
            float4 Lv = shfl4(v3, lsrcL);
            float4 Rv = shfl4(v3, lsrcR);
            float4 vm4 = f4max2(f4max2(Lv, Rv), v3);     // full 3x3 max (exact)
            if (pre) {
                const int yo = y0 + k;
                float vv[4] = { ctr.x, ctr.y, ctr.z, ctr.w };
                float mm[4] = { vm4.x, vm4.y, vm4.z, vm4.w };
                #pragma unroll
                for (int c = 0; c < 4; ++c) {
                    float v = vv[c], vm = mm[c];
                    // logit prefilter band 1e-3 >> worst-case sigmoid
                    // rounding-collision window (~1.5e-5)
                    if (v > 2.9f && (vm - v) <= 1e-3f) {
                        float sc = sigmoidf(v);
                        float sm = sigmoidf(vm);         // monotone: = max sigmoid
                        if (sc == sm && sc > THRESH) {
                            unsigned ib = ((unsigned)(yo * W + xg)) * NC + cbase + c;
                            unsigned long long key =
                                ((unsigned long long)__float_as_uint(sc) << 32) |
                                (unsigned long long)(0xFFFFFFFFu - ib);
                            int p = atomicAdd(&lcnt, 1);     // LDS atomic (lgkm)
                            if (p < LBUF) lbuf[p] = key;     // LDS write (lgkm)
                        }
                    }
                }
            }
        }
        pair = f4max2(ctr, bot);                         // pair for next step
    };

    // step k: ctr=row k+1 (slot (k+1)&7), bot=row k+2, fill slot (k+7)&7.
    step(w1, w2, w7, 0);   step(w2, w3, w0, 1);   step(w3, w4, w1, 2);
    step(w4, w5, w2, 3);   step(w5, w6, w3, 4);   step(w6, w7, w4, 5);
    step(w7, w0, w5, 6);   step(w0, w1, w6, 7);   step(w1, w2, w7, 8);
    step(w2, w3, w0, 9);   step(w3, w4, w1, 10);  step(w4, w5, w2, 11);
    step(w5, w6, w3, 12);  step(w6, w7, w4, 13);  step(w7, w0, w5, 14);
    step(w0, w1, w6, 15);

    // ---- block flush: ONE global atomic, then coalesced stores ----
    __syncthreads();
    int m = lcnt < LBUF ? lcnt : LBUF;
    if (tid == 0 && m > 0) sbase = atomicAdd(cnt_p, m);
    __syncthreads();
    for (int i = tid; i < m; i += 320) {
        int slot = sbase + i;
        if (slot < SEGCAP) seg_p[slot] = lbuf[i];
    }
}

// Stage B: per-batch exact top-K over 16 segments
// (histogram cutoff -> collect -> rank-by-count -> decode)
__global__ __launch_bounds__(256) void topk_kernel(const float* __restrict__ dxy,
                                                   const float* __restrict__ swh,
                                                   float* __restrict__ out) {
    const int b = blockIdx.x;
    const int tid = threadIdx.x;
    __shared__ int hist[NBINS];
    __shared__ int csum[256];
    __shared__ int segn[NSUB];
    __shared__ unsigned long long list[LISTCAP];
    __shared__ int lcount;
    __shared__ int kstar;

    if (tid < NSUB) {
        int n = g_counts[(b * NSUB + tid) * 16];
        segn[tid] = n > SEGCAP ? SEGCAP : n;
    }
    for (int i = tid; i < NBINS; i += 256) hist[i] = 0;
    if (tid == 0) lcount = 0;
    __syncthreads();

    const float SCALE = (float)NBINS / (1.0f - THRESH);
    #pragma unroll 1
    for (int s = 0; s < NSUB; ++s) {
        const unsigned long long* cb = g_cand + (size_t)(b * NSUB + s) * SEGCAP;
        const int n = segn[s];
        for (int i = tid; i < n; i += 256) {
            float v = __uint_as_float((unsigned)(cb[i] >> 32));
            int bin = (int)((v - THRESH) * SCALE);
            bin = bin < 0 ? 0 : (bin > NBINS - 1 ? NBINS - 1 : bin);
            atomicAdd(&hist[bin], 1);
        }
    }
    __syncthreads();

    int s0 = 0;
    for (int j = 0; j < NBINS / 256; j++) s0 += hist[tid * (NBINS / 256) + j];
    csum[tid] = s0;
    __syncthreads();

    if (tid == 0) {
        int acc = 0;
        int chunk = 255;
        for (; chunk >= 0; chunk--) {
            if (acc + csum[chunk] >= K) break;
            acc += csum[chunk];
        }
        int ks = 0;
        if (chunk >= 0) {
            int j = NBINS / 256 - 1;
            for (; j >= 0; j--) {
                acc += hist[chunk * (NBINS / 256) + j];
                if (acc >= K) break;
            }
            if (j < 0) j = 0;
            ks = chunk * (NBINS / 256) + j;
        }
        kstar = ks;
    }
    __syncthreads();

    const int ks = kstar;
    #pragma unroll 1
    for (int s = 0; s < NSUB; ++s) {
        const unsigned long long* cb = g_cand + (size_t)(b * NSUB + s) * SEGCAP;
        const int n = segn[s];
        for (int i = tid; i < n; i += 256) {
            unsigned long long key = cb[i];
            float v = __uint_as_float((unsigned)(key >> 32));
            int bin = (int)((v - THRESH) * SCALE);
            bin = bin < 0 ? 0 : (bin > NBINS - 1 ? NBINS - 1 : bin);
            if (bin >= ks) {
                int p = atomicAdd(&lcount, 1);
                if (p < LISTCAP) list[p] = key;
            }
        }
    }
    __syncthreads();
    const int M = lcount < LISTCAP ? lcount : LISTCAP;

    // exact rank by counting (keys distinct: low 32 bits unique per batch)
    for (int i = tid; i < M; i += 256) {
        unsigned long long key = list[i];
        int rank = 0;
        for (int j = 0; j < M; j++) rank += (list[j] > key);
        if (rank < K) {
            float conf = __uint_as_float((unsigned)(key >> 32));
            unsigned ib = 0xFFFFFFFFu - (unsigned)(key & 0xFFFFFFFFu);
            unsigned cls_i = ib % (unsigned)NC;
            unsigned sidx = ib / (unsigned)NC;
            unsigned xq = sidx & (W - 1);
            unsigned yq = sidx >> 7;

            size_t goff = ((size_t)b * (H * W) + sidx) * 2;
            float dx = dxy[goff], dy = dxy[goff + 1];
            float sw = swh[goff], sh = swh[goff + 1];

            float xs = (float)xq + dx;
            float ys = (float)yq + dy;
            float hw = sw * 0.5f;
            float hh = sh * 0.5f;
            const float invW = 1.0f / (float)W;
            const float invH = 1.0f / (float)H;

            int r = b * K + rank;
            out[r * 4 + 0] = (xs - hw) * invW;
            out[r * 4 + 1] = (ys - hh) * invH;
            out[r * 4 + 2] = (xs + hw) * invW;
            out[r * 4 + 3] = (ys + hh) * invH;
            out[B * K * 4 + r] = conf;
            out[B * K * 4 + B * K + r] = (float)cls_i;
        }
    }

    __syncthreads();
    if (tid < NSUB) g_counts[(b * NSUB + tid) * 16] = 0;   // reset for next call
}

extern "C" void kernel_launch(void* const* d_in, const int* in_sizes, int n_in,
                              void* d_out, int out_size, void* d_ws, size_t ws_size,
                              hipStream_t stream) {
    const float* cls = (const float*)d_in[0];
    const float* dxy = (const float*)d_in[1];
    const float* swh = (const float*)d_in[2];
    float* out = (float*)d_out;

    peak_kernel<<<NBLK, 320, 0, stream>>>(cls);
    topk_kernel<<<B, 256, 0, stream>>>(dxy, swh, out);
}